// Round 2
// baseline (846.333 us; speedup 1.0000x reference)
//
#include <hip/hip_runtime.h>

// Cost volume: out (B, 2C, D, H, W), fp32
//   c2 <  C: out = mask ? left[b,c2,h,x]        : 0
//   c2 >= C: out = mask ? right[b,c2-C,h,x-d]   : 0,  d = di + MIN_DISP
// Write-bound: 805 MB out vs 16 MB in. One wave = one W=256 row (float4/lane).

constexpr int MIN_DISP = -8;
constexpr int B = 2, C = 32, H = 128, W = 256, D = 48;

typedef float vf4 __attribute__((ext_vector_type(4)));  // native vec: nontemporal-store OK

__global__ __launch_bounds__(256) void cost_volume_kernel(
    const float* __restrict__ left, const float* __restrict__ right,
    float* __restrict__ out) {
    const int lane = threadIdx.x & 63;
    const int wv   = threadIdx.x >> 6;
    const int h    = blockIdx.x * 4 + wv;   // H/4 blocks * 4 waves
    const int di   = blockIdx.y;            // 0..D-1
    const int z    = blockIdx.z;            // b*2C + c2
    const int c2   = z & 63;
    const int b    = z >> 6;

    const int d  = di + MIN_DISP;           // -8..39
    const int xi = lane << 2;               // 0..252, 4 floats per lane

    const int cc = (c2 < C) ? c2 : (c2 - C);
    const size_t in_row = ((size_t)((b * C + cc) * H + h)) * W;

    vf4 v;
    if (c2 < C) {
        // left branch: aligned vector load, mask out-of-range lanes
        v = *(const vf4*)(left + in_row + xi);
#pragma unroll
        for (int j = 0; j < 4; ++j) {
            const int xs = xi + j - d;
            if (xs < 0 || xs >= W) v[j] = 0.0f;
        }
    } else {
        // right branch: shifted gather (cache-resident), masked
#pragma unroll
        for (int j = 0; j < 4; ++j) {
            const int xs = xi + j - d;
            v[j] = (xs >= 0 && xs < W) ? right[in_row + xs] : 0.0f;
        }
    }

    // out index: ((z*D + di)*H + h)*W + xi   (z == b*2C + c2)
    const size_t oidx = ((((size_t)z * D + di) * H + h) * (size_t)W) + xi;
    __builtin_nontemporal_store(v, (vf4*)(out + oidx));
}

extern "C" void kernel_launch(void* const* d_in, const int* in_sizes, int n_in,
                              void* d_out, int out_size, void* d_ws, size_t ws_size,
                              hipStream_t stream) {
    const float* left  = (const float*)d_in[0];
    const float* right = (const float*)d_in[1];
    float* out = (float*)d_out;

    dim3 grid(H / 4, D, B * 2 * C);  // (32, 48, 128)
    cost_volume_kernel<<<grid, 256, 0, stream>>>(left, right, out);
}